// Round 3
// baseline (238.832 us; speedup 1.0000x reference)
//
#include <hip/hip_runtime.h>
#include <math.h>

// ReRanker: B=256 docs, C=128 candidates each, D=1024 dims, f32.
// inner_score restructured: sum_k cos(c,k) = dot(chat_c, sum_k chat_k)
// -> O(B*C*D) instead of O(B*C^2*D).

#define EPS 1e-8f
constexpr int B = 256;
constexpr int C = 128;
constexpr int D = 1024;

__device__ __forceinline__ float waveReduceSum(float v) {
    // full 64-lane wave reduction
    v += __shfl_down(v, 32, 64);
    v += __shfl_down(v, 16, 64);
    v += __shfl_down(v, 8, 64);
    v += __shfl_down(v, 4, 64);
    v += __shfl_down(v, 2, 64);
    v += __shfl_down(v, 1, 64);
    return v;
}

// K0: per-b doc/summary norms, summary_score; zero summary_avg accumulator.
__global__ __launch_bounds__(256) void k0_norms(
    const float* __restrict__ doc, const float* __restrict__ summ,
    float* __restrict__ dn_inv, float* __restrict__ sn_inv,
    float* __restrict__ out_sumscore, float* __restrict__ out_sumavg) {
    const int b = blockIdx.x;
    const int t = threadIdx.x;
    const float4 dv = ((const float4*)(doc + (size_t)b * D))[t];
    const float4 sv = ((const float4*)(summ + (size_t)b * D))[t];
    float dd = dv.x * dv.x + dv.y * dv.y + dv.z * dv.z + dv.w * dv.w;
    float ss = sv.x * sv.x + sv.y * sv.y + sv.z * sv.z + sv.w * sv.w;
    float sd = sv.x * dv.x + sv.y * dv.y + sv.z * dv.z + sv.w * dv.w;
    dd = waveReduceSum(dd);
    ss = waveReduceSum(ss);
    sd = waveReduceSum(sd);
    __shared__ float red[3][4];
    const int wave = t >> 6, lane = t & 63;
    if (lane == 0) { red[0][wave] = dd; red[1][wave] = ss; red[2][wave] = sd; }
    __syncthreads();
    if (t == 0) {
        const float DD = red[0][0] + red[0][1] + red[0][2] + red[0][3];
        const float SS = red[1][0] + red[1][1] + red[1][2] + red[1][3];
        const float SD = red[2][0] + red[2][1] + red[2][2] + red[2][3];
        const float di = 1.0f / fmaxf(sqrtf(DD), EPS);
        const float si = 1.0f / fmaxf(sqrtf(SS), EPS);
        dn_inv[b] = di;
        sn_inv[b] = si;
        out_sumscore[b] = SD * di * si;
        out_sumavg[b] = 0.0f;  // d_ws/d_out poisoned 0xAA -> must init before atomics
    }
}

// K1: one wave per (b,c). Computes ||cand||, cand.doc, cand.summary in a single
// pass over the candidate row. 4 waves/block share doc+summary rows via LDS.
__global__ __launch_bounds__(256) void k1_cand(
    const float* __restrict__ cand, const float* __restrict__ doc,
    const float* __restrict__ summ, const float* __restrict__ dn_inv,
    const float* __restrict__ sn_inv, float* __restrict__ inv_cn,
    float* __restrict__ out_outer, float* __restrict__ out_sumavg) {
    const int blk = blockIdx.x;       // b*32 + g
    const int b = blk >> 5;
    const int g = blk & 31;
    const int t = threadIdx.x;
    const int wave = t >> 6, lane = t & 63;
    const int c = g * 4 + wave;

    __shared__ float4 doc_s[D / 4];
    __shared__ float4 sum_s[D / 4];
    doc_s[t] = ((const float4*)(doc + (size_t)b * D))[t];
    sum_s[t] = ((const float4*)(summ + (size_t)b * D))[t];
    __syncthreads();

    const float4* cp = (const float4*)(cand + ((size_t)b * C + c) * D);
    float cd = 0.0f, cs = 0.0f, cc = 0.0f;
#pragma unroll
    for (int q = 0; q < 4; ++q) {
        const float4 cv = cp[lane + 64 * q];
        const float4 dv = doc_s[lane + 64 * q];
        const float4 sv = sum_s[lane + 64 * q];
        cd += cv.x * dv.x + cv.y * dv.y + cv.z * dv.z + cv.w * dv.w;
        cs += cv.x * sv.x + cv.y * sv.y + cv.z * sv.z + cv.w * sv.w;
        cc += cv.x * cv.x + cv.y * cv.y + cv.z * cv.z + cv.w * cv.w;
    }
    cd = waveReduceSum(cd);
    cs = waveReduceSum(cs);
    cc = waveReduceSum(cc);

    __shared__ float scs[4];
    if (lane == 0) {
        const float ic = 1.0f / fmaxf(sqrtf(cc), EPS);
        inv_cn[b * C + c] = ic;
        out_outer[b * C + c] = cd * ic * dn_inv[b];
        scs[wave] = cs * ic * sn_inv[b];
    }
    __syncthreads();
    if (t == 0) {
        atomicAdd(&out_sumavg[b],
                  (scs[0] + scs[1] + scs[2] + scs[3]) * (1.0f / C));
    }
}

// K2: s[b,:] = sum_c cand[b,c,:] * inv_cn[b,c]. One block per b; each thread
// owns one float4 column slice; iterate c with fully coalesced 4 KiB reads.
__global__ __launch_bounds__(256) void k2_chatsum(
    const float* __restrict__ cand, const float* __restrict__ inv_cn,
    float* __restrict__ s) {
    const int b = blockIdx.x;
    const int t = threadIdx.x;
    __shared__ float ic[C];
    if (t < C) ic[t] = inv_cn[b * C + t];
    __syncthreads();
    const float4* cp = (const float4*)(cand + (size_t)b * C * D);
    float4 acc = make_float4(0.0f, 0.0f, 0.0f, 0.0f);
    for (int c = 0; c < C; ++c) {
        const float4 v = cp[c * (D / 4) + t];
        const float w = ic[c];
        acc.x += v.x * w;
        acc.y += v.y * w;
        acc.z += v.z * w;
        acc.w += v.w * w;
    }
    ((float4*)(s + (size_t)b * D))[t] = acc;
}

// K3: one wave per (b,c): t = dot(cand[b,c], s[b]);
// inner = (t*inv_cn - 1)/(C-1). s[b] staged in LDS per block.
__global__ __launch_bounds__(256) void k3_inner(
    const float* __restrict__ cand, const float* __restrict__ s,
    const float* __restrict__ inv_cn, float* __restrict__ out_inner) {
    const int blk = blockIdx.x;
    const int b = blk >> 5;
    const int g = blk & 31;
    const int t = threadIdx.x;
    const int wave = t >> 6, lane = t & 63;
    const int c = g * 4 + wave;

    __shared__ float4 s_s[D / 4];
    s_s[t] = ((const float4*)(s + (size_t)b * D))[t];
    __syncthreads();

    const float4* cp = (const float4*)(cand + ((size_t)b * C + c) * D);
    float td = 0.0f;
#pragma unroll
    for (int q = 0; q < 4; ++q) {
        const float4 cv = cp[lane + 64 * q];
        const float4 sv = s_s[lane + 64 * q];
        td += cv.x * sv.x + cv.y * sv.y + cv.z * sv.z + cv.w * sv.w;
    }
    td = waveReduceSum(td);
    if (lane == 0) {
        out_inner[b * C + c] =
            (td * inv_cn[b * C + c] - 1.0f) * (1.0f / (C - 1));
    }
}

extern "C" void kernel_launch(void* const* d_in, const int* in_sizes, int n_in,
                              void* d_out, int out_size, void* d_ws,
                              size_t ws_size, hipStream_t stream) {
    const float* doc = (const float*)d_in[0];       // [B, D]
    const float* summ = (const float*)d_in[1];      // [B, D]
    const float* cand = (const float*)d_in[2];      // [B, C, D]

    float* out = (float*)d_out;
    float* out_outer = out;                // [B*C]
    float* out_inner = out + B * C;        // [B*C]
    float* out_sumscore = out + 2 * B * C; // [B]
    float* out_sumavg = out + 2 * B * C + B; // [B]

    float* ws = (float*)d_ws;
    float* dn_inv = ws;                 // B
    float* sn_inv = ws + B;             // B
    float* inv_cn = ws + 2 * B;         // B*C
    float* s = ws + 2 * B + B * C;      // B*D

    k0_norms<<<B, 256, 0, stream>>>(doc, summ, dn_inv, sn_inv, out_sumscore,
                                    out_sumavg);
    k1_cand<<<B * (C / 4), 256, 0, stream>>>(cand, doc, summ, dn_inv, sn_inv,
                                             inv_cn, out_outer, out_sumavg);
    k2_chatsum<<<B, 256, 0, stream>>>(cand, inv_cn, s);
    k3_inner<<<B * (C / 4), 256, 0, stream>>>(cand, s, inv_cn, out_inner);
}

// Round 5
// 213.891 us; speedup vs baseline: 1.1166x; 1.1166x over previous
//
#include <hip/hip_runtime.h>
#include <math.h>

// ReRanker fused single-kernel: B=256, C=128, D=1024, f32.
// inner_score via Gram factorization: sum_k cos(c,k) = dot(chat_c, sum_k chat_k).
// One block per b, 1024 threads (16 waves). Phase 1: doc/summ norms (wave-
// uniform, no LDS). Phase 2: one pass over cand rows -> norms, outer,
// summary_avg, weighted column-sum partials. Phase 3: second pass (L2/L3-hot)
// -> inner. No atomics, no workspace, fully deterministic.

#define EPS 1e-8f
constexpr int B = 256;
constexpr int C = 128;
constexpr int D = 1024;
constexpr int NW = 16;        // waves per block
constexpr int CPW = C / NW;   // 8 candidate rows per wave

__device__ __forceinline__ float bflySum(float v) {
    // butterfly: ALL 64 lanes end with the total
    v += __shfl_xor(v, 1, 64);
    v += __shfl_xor(v, 2, 64);
    v += __shfl_xor(v, 4, 64);
    v += __shfl_xor(v, 8, 64);
    v += __shfl_xor(v, 16, 64);
    v += __shfl_xor(v, 32, 64);
    return v;
}

__device__ __forceinline__ float dot4(const float4 a, const float4 b) {
    return a.x * b.x + a.y * b.y + a.z * b.z + a.w * b.w;
}

__global__ __launch_bounds__(1024) void rerank_all(
    const float* __restrict__ doc, const float* __restrict__ summ,
    const float* __restrict__ cand, float* __restrict__ out_outer,
    float* __restrict__ out_inner, float* __restrict__ out_sumscore,
    float* __restrict__ out_sumavg) {
    const int b = blockIdx.x;
    const int t = threadIdx.x;
    const int wave = t >> 6;
    const int lane = t & 63;

    __shared__ float s_part[NW][D];  // 64 KiB: per-wave partial column sums
    __shared__ float s_full[D];      // 4 KiB: reduced column sum
    __shared__ float ic_lds[C];      // 1/||cand|| per c
    __shared__ float sa_lds[NW];     // per-wave summary_avg partials

    // ---- Phase 1: doc/summary norms + summary_score (wave-uniform) ----
    const float4* dp = (const float4*)(doc + (size_t)b * D);
    const float4* sp = (const float4*)(summ + (size_t)b * D);
    float4 d4[4], m4[4];
#pragma unroll
    for (int q = 0; q < 4; ++q) {
        d4[q] = dp[lane + 64 * q];
        m4[q] = sp[lane + 64 * q];
    }
    float dd = 0.0f, ss = 0.0f, sd = 0.0f;
#pragma unroll
    for (int q = 0; q < 4; ++q) {
        dd += dot4(d4[q], d4[q]);
        ss += dot4(m4[q], m4[q]);
        sd += dot4(m4[q], d4[q]);
    }
    dd = bflySum(dd);
    ss = bflySum(ss);
    sd = bflySum(sd);
    const float di = 1.0f / fmaxf(sqrtf(dd), EPS);
    const float si = 1.0f / fmaxf(sqrtf(ss), EPS);
    if (t == 0) out_sumscore[b] = sd * di * si;

    // ---- Phase 2: first pass over candidate rows ----
    const float4* cb = (const float4*)(cand + (size_t)b * C * D);
    float4 s_prv[4];
#pragma unroll
    for (int q = 0; q < 4; ++q) s_prv[q] = make_float4(0.f, 0.f, 0.f, 0.f);
    float sa_acc = 0.0f;

#pragma unroll 2
    for (int i = 0; i < CPW; ++i) {
        const int c = wave * CPW + i;
        const float4* cp = cb + (size_t)c * (D / 4);
        float4 cv[4];
#pragma unroll
        for (int q = 0; q < 4; ++q) cv[q] = cp[lane + 64 * q];
        float cc = 0.0f, cd = 0.0f, cs = 0.0f;
#pragma unroll
        for (int q = 0; q < 4; ++q) {
            cc += dot4(cv[q], cv[q]);
            cd += dot4(cv[q], d4[q]);
            cs += dot4(cv[q], m4[q]);
        }
        cc = bflySum(cc);
        cd = bflySum(cd);
        cs = bflySum(cs);
        const float icv = 1.0f / fmaxf(sqrtf(cc), EPS);  // all lanes
        if (lane == 0) {
            ic_lds[c] = icv;
            out_outer[b * C + c] = cd * icv * di;
        }
        sa_acc += cs * icv;  // wave-uniform
#pragma unroll
        for (int q = 0; q < 4; ++q) {
            s_prv[q].x += cv[q].x * icv;
            s_prv[q].y += cv[q].y * icv;
            s_prv[q].z += cv[q].z * icv;
            s_prv[q].w += cv[q].w * icv;
        }
    }
#pragma unroll
    for (int q = 0; q < 4; ++q)
        ((float4*)s_part[wave])[lane + 64 * q] = s_prv[q];
    if (lane == 0) sa_lds[wave] = sa_acc;
    __syncthreads();

    // reduce 16 wave partials: thread t owns column t (conflict-free)
    float colsum = 0.0f;
#pragma unroll
    for (int w = 0; w < NW; ++w) colsum += s_part[w][t];
    s_full[t] = colsum;
    if (t == 0) {
        float S = 0.0f;
#pragma unroll
        for (int w = 0; w < NW; ++w) S += sa_lds[w];
        out_sumavg[b] = S * si * (1.0f / C);
    }
    __syncthreads();

    // ---- Phase 3: second pass (cache-hot) -> inner ----
    float4 s4[4];
#pragma unroll
    for (int q = 0; q < 4; ++q) s4[q] = ((const float4*)s_full)[lane + 64 * q];

#pragma unroll 2
    for (int i = 0; i < CPW; ++i) {
        const int c = wave * CPW + i;
        const float4* cp = cb + (size_t)c * (D / 4);
        float td = 0.0f;
#pragma unroll
        for (int q = 0; q < 4; ++q) {
            const float4 cv = cp[lane + 64 * q];
            td += dot4(cv, s4[q]);
        }
        td = bflySum(td);
        if (lane == 0)
            out_inner[b * C + c] =
                (td * ic_lds[c] - 1.0f) * (1.0f / (C - 1));
    }
}

extern "C" void kernel_launch(void* const* d_in, const int* in_sizes, int n_in,
                              void* d_out, int out_size, void* d_ws,
                              size_t ws_size, hipStream_t stream) {
    const float* doc = (const float*)d_in[0];   // [B, D]
    const float* summ = (const float*)d_in[1];  // [B, D]
    const float* cand = (const float*)d_in[2];  // [B, C, D]

    float* out = (float*)d_out;
    float* out_outer = out;                    // [B*C]
    float* out_inner = out + B * C;            // [B*C]
    float* out_sumscore = out + 2 * B * C;     // [B]
    float* out_sumavg = out + 2 * B * C + B;   // [B]

    rerank_all<<<B, 1024, 0, stream>>>(doc, summ, cand, out_outer, out_inner,
                                       out_sumscore, out_sumavg);
}